// Round 4
// baseline (223.120 us; speedup 1.0000x reference)
//
#include <hip/hip_runtime.h>

// HierarchicalClassifier: B=16384, D=2048, N_TOP=8, N_CLASS=16
// out[b, t*16+c] = sigmoid(f.top_W[t]+top_b[t]) * softmax_c(f.bottom_W[t,:,c]+bot_b[t,c])
//
// R10: volatile-asm pinned pipeline. R7/R8/R9 post-mortems: hipcc sinks
// register global-loads to just-before-use regardless of source order (R7),
// locals-per-step (R8, VGPR=52 proof), or per-step __syncthreads (R9 — barriers
// force no vmcnt drain for loads, only for stores/LDS). Counters: MfmaUtil
// 4.5%, HBM 12.6%, dur invariant to L3 residency -> pure load-latency
// serialization at ~3x the memory floor. Fix: loads as `asm volatile`
// global_load_dwordx4 (order pinned), explicit counted `s_waitcnt vmcnt(2)`
// + sched_barrier(0) per rule #18. Step s: wait(2) [drains B(s),A(s); A(s+1)
// stays in flight] -> 9 MFMA -> issue B(s+1) (WAR single-buffer) -> issue
// A(s+2). A gets 2 steps of latency cover (HBM ~900cy), B one L2 round-trip
// absorbed by 4 waves/SIMD. ~105 VGPR -> (256,4), 16 waves/CU, 1024 blocks
// co-resident. K order unchanged -> bit-identical numerics.

#define D_DIM 2048
#define NTILE 9          // 144 columns / 16
#define M_ROWS 16        // rows per workgroup (1 row-tile)

using f32x4 = float __attribute__((ext_vector_type(4)));
using half8 = _Float16 __attribute__((ext_vector_type(8)));
using fp16x2 = __fp16 __attribute__((ext_vector_type(2)));

// Swizzled B layout: S[(((w*16 + ks)*9 + nt)*64 + lane)*8 + j]
//   = W[n = nt*16 + (lane&15)][k = w*512 + ks*32 + (lane>>4)*8 + j]
// W rows 0..7 = top_W, 8..135 = bottom_W[t][:,c] (n-8 = t*16+c), 136..143 = 0.
__global__ void prep_weights(const float* __restrict__ topW,
                             const float* __restrict__ botW,
                             _Float16* __restrict__ S) {
    int idx = blockIdx.x * blockDim.x + threadIdx.x;   // [0, 4*16*9*64)
    if (idx >= 4 * 16 * NTILE * 64) return;
    int lane = idx & 63;
    int tmp  = idx >> 6;          // (w*16+ks)*9 + nt
    int nt   = tmp % NTILE;
    int wks  = tmp / NTILE;       // w*16+ks in [0,64)
    int n     = nt * 16 + (lane & 15);
    int kbase = wks * 32 + (lane >> 4) * 8;

    _Float16 v[8];
    #pragma unroll
    for (int j = 0; j < 8; j++) {
        int k = kbase + j;
        float x = 0.0f;
        if (n < 8) {
            x = topW[n * D_DIM + k];
        } else if (n < 136) {
            int t = (n - 8) >> 4, c = (n - 8) & 15;
            x = botW[(t * D_DIM + k) * 16 + c];
        }
        v[j] = (_Float16)x;
    }
    *(half8*)(S + (size_t)idx * 8) = *(half8*)v;
}

static __device__ __forceinline__ half8 pack_af(f32x4 a, f32x4 b) {
    fp16x2 p0 = __builtin_amdgcn_cvt_pkrtz(a[0], a[1]);
    fp16x2 p1 = __builtin_amdgcn_cvt_pkrtz(a[2], a[3]);
    fp16x2 p2 = __builtin_amdgcn_cvt_pkrtz(b[0], b[1]);
    fp16x2 p3 = __builtin_amdgcn_cvt_pkrtz(b[2], b[3]);
    half8 r;
    r[0] = (_Float16)p0[0]; r[1] = (_Float16)p0[1];
    r[2] = (_Float16)p1[0]; r[3] = (_Float16)p1[1];
    r[4] = (_Float16)p2[0]; r[5] = (_Float16)p2[1];
    r[6] = (_Float16)p3[0]; r[7] = (_Float16)p3[1];
    return r;
}

// Pinned global load: saddr (SGPR pair) + 32-bit voffset + 13-bit signed imm.
#define GL4(dst, voff, sbase, IMM)                                         \
    asm volatile("global_load_dwordx4 %0, %1, %2 offset:%3"                \
                 : "=v"(dst) : "v"(voff), "s"(sbase), "i"(IMM))

#define VWAIT(N) do {                                                      \
        asm volatile("s_waitcnt vmcnt(%0)" :: "i"(N) : "memory");          \
        __builtin_amdgcn_sched_barrier(0);                                 \
    } while (0)

__global__ __launch_bounds__(256, 4) void hc_fused(
        const float* __restrict__ feat, const _Float16* __restrict__ Bsw,
        const float* __restrict__ top_b, const float* __restrict__ bot_b,
        float* __restrict__ out) {
    __shared__ float red[4][M_ROWS][148];   // [wave][row][ncol(+pad)] = 37.9 KB

    const int tid  = threadIdx.x;
    const int lane = tid & 63, wave = tid >> 6;
    const int quad = lane >> 4, low = lane & 15;
    const size_t row0 = (size_t)blockIdx.x * M_ROWS;

    // Scalar bases (kernel args -> SGPRs); all wave-dependence in voffsets.
    const unsigned long long sA = (unsigned long long)feat;
    const unsigned long long sB = (unsigned long long)Bsw;
    // A: lane reads feat[row0+low][wave*512 + quad*8 + ks*32 + {0..7}]
    const unsigned vAoff = (unsigned)(((row0 + low) * D_DIM + wave * 512 + quad * 8) * 4);
    // B: byte offset (((wave*16+ks)*9 + nt)*64 + lane)*16
    const unsigned vBoff = (unsigned)(wave * 147456 + lane * 16);

    f32x4 acc[NTILE];
    #pragma unroll
    for (int i = 0; i < NTILE; i++) acc[i] = (f32x4)0.0f;

    f32x4 b0_, b1_, b2_, b3_, b4_, b5_, b6_, b7_, b8_;   // single B set (WAR reuse)
    f32x4 aX0, aX1, aY0, aY1;                             // A double buffer

#define ISSUE_B(KS) do {                                                   \
        unsigned off_lo_ = vBoff + ((KS) * 9216 + 2048);                   \
        unsigned off_hi_ = vBoff + ((KS) * 9216 + 6144);                   \
        GL4(b0_, off_lo_, sB, -2048);                                      \
        GL4(b1_, off_lo_, sB, -1024);                                      \
        GL4(b2_, off_lo_, sB,     0);                                      \
        GL4(b3_, off_lo_, sB,  1024);                                      \
        GL4(b4_, off_hi_, sB, -2048);                                      \
        GL4(b5_, off_hi_, sB, -1024);                                      \
        GL4(b6_, off_hi_, sB,     0);                                      \
        GL4(b7_, off_hi_, sB,  1024);                                      \
        GL4(b8_, off_hi_, sB,  2048);                                      \
    } while (0)

#define COMP(AL0, AL1) do {                                                \
        const half8 af_ = pack_af(AL0, AL1);                               \
        acc[0] = __builtin_amdgcn_mfma_f32_16x16x32_f16(af_, __builtin_bit_cast(half8, b0_), acc[0], 0, 0, 0); \
        acc[1] = __builtin_amdgcn_mfma_f32_16x16x32_f16(af_, __builtin_bit_cast(half8, b1_), acc[1], 0, 0, 0); \
        acc[2] = __builtin_amdgcn_mfma_f32_16x16x32_f16(af_, __builtin_bit_cast(half8, b2_), acc[2], 0, 0, 0); \
        acc[3] = __builtin_amdgcn_mfma_f32_16x16x32_f16(af_, __builtin_bit_cast(half8, b3_), acc[3], 0, 0, 0); \
        acc[4] = __builtin_amdgcn_mfma_f32_16x16x32_f16(af_, __builtin_bit_cast(half8, b4_), acc[4], 0, 0, 0); \
        acc[5] = __builtin_amdgcn_mfma_f32_16x16x32_f16(af_, __builtin_bit_cast(half8, b5_), acc[5], 0, 0, 0); \
        acc[6] = __builtin_amdgcn_mfma_f32_16x16x32_f16(af_, __builtin_bit_cast(half8, b6_), acc[6], 0, 0, 0); \
        acc[7] = __builtin_amdgcn_mfma_f32_16x16x32_f16(af_, __builtin_bit_cast(half8, b7_), acc[7], 0, 0, 0); \
        acc[8] = __builtin_amdgcn_mfma_f32_16x16x32_f16(af_, __builtin_bit_cast(half8, b8_), acc[8], 0, 0, 0); \
        __builtin_amdgcn_sched_barrier(0);                                 \
    } while (0)

    // Prologue: queue (oldest->newest) = B0 x9, A0 x2, A1 x2  (13 in flight)
    ISSUE_B(0);
    GL4(aX0, vAoff, sA,   0);  GL4(aX1, vAoff, sA,  16);
    GL4(aY0, vAoff, sA, 128);  GL4(aY1, vAoff, sA, 144);

    // Step s: VWAIT(2) drains B(s)+A(s), leaves A(s+1); compute; refill.
    VWAIT(2); COMP(aX0, aX1); ISSUE_B( 1); GL4(aX0, vAoff, sA,  256); GL4(aX1, vAoff, sA,  272);  // s=0
    VWAIT(2); COMP(aY0, aY1); ISSUE_B( 2); GL4(aY0, vAoff, sA,  384); GL4(aY1, vAoff, sA,  400);  // s=1
    VWAIT(2); COMP(aX0, aX1); ISSUE_B( 3); GL4(aX0, vAoff, sA,  512); GL4(aX1, vAoff, sA,  528);  // s=2
    VWAIT(2); COMP(aY0, aY1); ISSUE_B( 4); GL4(aY0, vAoff, sA,  640); GL4(aY1, vAoff, sA,  656);  // s=3
    VWAIT(2); COMP(aX0, aX1); ISSUE_B( 5); GL4(aX0, vAoff, sA,  768); GL4(aX1, vAoff, sA,  784);  // s=4
    VWAIT(2); COMP(aY0, aY1); ISSUE_B( 6); GL4(aY0, vAoff, sA,  896); GL4(aY1, vAoff, sA,  912);  // s=5
    VWAIT(2); COMP(aX0, aX1); ISSUE_B( 7); GL4(aX0, vAoff, sA, 1024); GL4(aX1, vAoff, sA, 1040);  // s=6
    VWAIT(2); COMP(aY0, aY1); ISSUE_B( 8); GL4(aY0, vAoff, sA, 1152); GL4(aY1, vAoff, sA, 1168);  // s=7
    VWAIT(2); COMP(aX0, aX1); ISSUE_B( 9); GL4(aX0, vAoff, sA, 1280); GL4(aX1, vAoff, sA, 1296);  // s=8
    VWAIT(2); COMP(aY0, aY1); ISSUE_B(10); GL4(aY0, vAoff, sA, 1408); GL4(aY1, vAoff, sA, 1424);  // s=9
    VWAIT(2); COMP(aX0, aX1); ISSUE_B(11); GL4(aX0, vAoff, sA, 1536); GL4(aX1, vAoff, sA, 1552);  // s=10
    VWAIT(2); COMP(aY0, aY1); ISSUE_B(12); GL4(aY0, vAoff, sA, 1664); GL4(aY1, vAoff, sA, 1680);  // s=11
    VWAIT(2); COMP(aX0, aX1); ISSUE_B(13); GL4(aX0, vAoff, sA, 1792); GL4(aX1, vAoff, sA, 1808);  // s=12
    VWAIT(2); COMP(aY0, aY1); ISSUE_B(14); GL4(aY0, vAoff, sA, 1920); GL4(aY1, vAoff, sA, 1936);  // s=13
    VWAIT(2); COMP(aX0, aX1); ISSUE_B(15);                                                        // s=14
    VWAIT(0); COMP(aY0, aY1);                                                                     // s=15

#undef ISSUE_B
#undef COMP

    // C/D layout (measured m89/m91): col = lane&15, row = quad*4 + reg.
    #pragma unroll
    for (int nt = 0; nt < NTILE; nt++) {
        #pragma unroll
        for (int r = 0; r < 4; r++) {
            red[wave][quad * 4 + r][nt * 16 + low] = acc[nt][r];
        }
    }
    __syncthreads();

    // Epilogue: threads 0..127 -> (row = tid>>3 in [0,16), top = tid&7).
    if (tid < 128) {
        const int row = tid >> 3;
        const int top = tid & 7;

        float zt = top_b[top];
        #pragma unroll
        for (int w = 0; w < 4; w++) zt += red[w][row][top];
        const float sig = 1.0f / (1.0f + __expf(-zt));

        float z[16];
        float zmax = -1e30f;
        #pragma unroll
        for (int c = 0; c < 16; c++) {
            float v = bot_b[top * 16 + c];
            #pragma unroll
            for (int w = 0; w < 4; w++) v += red[w][row][8 + top * 16 + c];
            z[c] = v;
            zmax = fmaxf(zmax, v);
        }
        float s = 0.0f;
        #pragma unroll
        for (int c = 0; c < 16; c++) { z[c] = __expf(z[c] - zmax); s += z[c]; }
        const float scale = sig / s;

        float* o = out + (row0 + row) * 128 + top * 16;
        #pragma unroll
        for (int c = 0; c < 16; c += 4) {
            f32x4 v = { z[c] * scale, z[c+1] * scale, z[c+2] * scale, z[c+3] * scale };
            *(f32x4*)(o + c) = v;
        }
    }
}

extern "C" void kernel_launch(void* const* d_in, const int* in_sizes, int n_in,
                              void* d_out, int out_size, void* d_ws, size_t ws_size,
                              hipStream_t stream) {
    const float* feat  = (const float*)d_in[0];   // (16384, 2048)
    const float* topW  = (const float*)d_in[1];   // (8, 2048)
    const float* topB  = (const float*)d_in[2];   // (8,)
    const float* botW  = (const float*)d_in[3];   // (8, 2048, 16)
    const float* botB  = (const float*)d_in[4];   // (8, 16)
    float* out = (float*)d_out;                   // (16384, 128)
    _Float16* Bsw = (_Float16*)d_ws;              // 144*2048 fp16 = 576 KB swizzled

    prep_weights<<<(4 * 16 * NTILE * 64 + 255) / 256, 256, 0, stream>>>(topW, botW, Bsw);
    hc_fused<<<16384 / M_ROWS, 256, 0, stream>>>(feat, Bsw, topB, botB, out);
}